// Round 1
// 1010.174 us; speedup vs baseline: 1.7718x; 1.7718x over previous
//
#include <hip/hip_runtime.h>
#include <math.h>

#define N_LEVELS 16
#define MAX_SIZE (1u << 19)   // 2^19 entries per level slab in `tables`

struct Params {
    float res[N_LEVELS];
    unsigned int mask[N_LEVELS];
};

// ---------------------------------------------------------------------------
// Phase 1: level-major gather. Grid = (blocks_per_level, 16). Blocks are
// dispatched x-fastest, so the resident window at any instant covers ONE
// level -> each XCD's 4 MB L2 holds exactly that level's table (fine levels
// are exactly 4 MB) -> gathers become L2 hits instead of fabric misses.
// Output ws[l][n] (float2), perfectly coalesced.
// ---------------------------------------------------------------------------
__global__ __launch_bounds__(256) void hashgrid_level_kernel(
    const float* __restrict__ x,
    const float* __restrict__ tables,
    float2* __restrict__ ws,          // [16][N] float2
    Params p, int N)
{
    int l = blockIdx.y;
    int n = blockIdx.x * 256 + threadIdx.x;
    if (n >= N) return;

    float res = p.res[l];
    unsigned int mask = p.mask[l];
    const float2* __restrict__ tab =
        reinterpret_cast<const float2*>(tables) + (size_t)l * MAX_SIZE;

    float px = x[n * 3 + 0];
    float py = x[n * 3 + 1];
    float pz = x[n * 3 + 2];

    // f32 semantics identical to reference: xs = x*res (f32), xi = floor, xf = xs - xi
    float xs = px * res, ys = py * res, zs = pz * res;
    float fxi = floorf(xs), fyi = floorf(ys), fzi = floorf(zs);
    float wx1 = xs - fxi, wy1 = ys - fyi, wz1 = zs - fzi;   // upper-corner weights
    float wx0 = 1.0f - wx1, wy0 = 1.0f - wy1, wz0 = 1.0f - wz1;

    unsigned int ix = (unsigned int)fxi;
    unsigned int iy = (unsigned int)fyi;
    unsigned int iz = (unsigned int)fzi;

    const unsigned int P2 = 2654435761u, P3 = 805459861u;
    unsigned int hx0 = ix;       unsigned int hx1 = ix + 1u;
    unsigned int hy0 = iy * P2;  unsigned int hy1 = hy0 + P2;   // (iy+1)*P2 mod 2^32
    unsigned int hz0 = iz * P3;  unsigned int hz1 = hz0 + P3;

    unsigned int hidx[8];
    float w[8];
#pragma unroll
    for (int c = 0; c < 8; ++c) {
        unsigned int hh = ((c & 1) ? hx1 : hx0)
                        ^ ((c & 2) ? hy1 : hy0)
                        ^ ((c & 4) ? hz1 : hz0);
        hidx[c] = hh & mask;
        w[c] = (((c & 1) ? wx1 : wx0) * ((c & 2) ? wy1 : wy0)) * ((c & 4) ? wz1 : wz0);
    }

    // Issue all 8 gathers before use -> 8 outstanding loads per thread.
    float2 v[8];
#pragma unroll
    for (int c = 0; c < 8; ++c) v[c] = tab[hidx[c]];

    float accx = 0.0f, accy = 0.0f;
#pragma unroll
    for (int c = 0; c < 8; ++c) {   // sequential sum order matches reference axis sum
        accx += v[c].x * w[c];
        accy += v[c].y * w[c];
    }

    ws[(size_t)l * N + n] = make_float2(accx, accy);
}

// ---------------------------------------------------------------------------
// Phase 2: transpose ws[l][n] -> out[n][l] via LDS tiles. Pure streaming:
// reads coalesced along n per level, writes 512B-contiguous runs per wave.
// ---------------------------------------------------------------------------
__global__ __launch_bounds__(256) void transpose_kernel(
    const float2* __restrict__ ws,
    float2* __restrict__ out,
    int N)
{
    __shared__ float2 lds[N_LEVELS][257];   // +1 pad: 4-way max bank aliasing
    int tid = threadIdx.x;
    int n0 = blockIdx.x * 256;
    int n = n0 + tid;

#pragma unroll
    for (int l = 0; l < N_LEVELS; ++l) {
        if (n < N) lds[l][tid] = ws[(size_t)l * N + n];
    }
    __syncthreads();

#pragma unroll
    for (int i = 0; i < 16; ++i) {
        int pn = i * 16 + (tid >> 4);   // point within tile
        int j  = tid & 15;              // level
        int np = n0 + pn;
        if (np < N) out[(size_t)np * 16 + j] = lds[j][pn];
    }
}

// ---------------------------------------------------------------------------
// Fallback (original proven kernel): one thread per (point, level).
// ---------------------------------------------------------------------------
__global__ __launch_bounds__(256) void hashgrid_kernel(
    const float* __restrict__ x,
    const float* __restrict__ tables,
    float2* __restrict__ out,
    Params p, int total)
{
    int t = blockIdx.x * 256 + threadIdx.x;
    if (t >= total) return;
    int l = t & 15;
    int n = t >> 4;

    float res = p.res[l];
    unsigned int mask = p.mask[l];
    const float2* __restrict__ tab =
        reinterpret_cast<const float2*>(tables) + (size_t)l * MAX_SIZE;

    float px = x[n * 3 + 0];
    float py = x[n * 3 + 1];
    float pz = x[n * 3 + 2];

    float xs = px * res, ys = py * res, zs = pz * res;
    float fxi = floorf(xs), fyi = floorf(ys), fzi = floorf(zs);
    float wx1 = xs - fxi, wy1 = ys - fyi, wz1 = zs - fzi;
    float wx0 = 1.0f - wx1, wy0 = 1.0f - wy1, wz0 = 1.0f - wz1;

    unsigned int ix = (unsigned int)fxi;
    unsigned int iy = (unsigned int)fyi;
    unsigned int iz = (unsigned int)fzi;

    const unsigned int P2 = 2654435761u, P3 = 805459861u;
    unsigned int hx0 = ix;       unsigned int hx1 = ix + 1u;
    unsigned int hy0 = iy * P2;  unsigned int hy1 = hy0 + P2;
    unsigned int hz0 = iz * P3;  unsigned int hz1 = hz0 + P3;

    unsigned int hidx[8];
    float w[8];
#pragma unroll
    for (int c = 0; c < 8; ++c) {
        unsigned int hh = ((c & 1) ? hx1 : hx0)
                        ^ ((c & 2) ? hy1 : hy0)
                        ^ ((c & 4) ? hz1 : hz0);
        hidx[c] = hh & mask;
        w[c] = (((c & 1) ? wx1 : wx0) * ((c & 2) ? wy1 : wy0)) * ((c & 4) ? wz1 : wz0);
    }

    float2 v[8];
#pragma unroll
    for (int c = 0; c < 8; ++c) v[c] = tab[hidx[c]];

    float accx = 0.0f, accy = 0.0f;
#pragma unroll
    for (int c = 0; c < 8; ++c) {
        accx += v[c].x * w[c];
        accy += v[c].y * w[c];
    }

    out[t] = make_float2(accx, accy);
}

extern "C" void kernel_launch(void* const* d_in, const int* in_sizes, int n_in,
                              void* d_out, int out_size, void* d_ws, size_t ws_size,
                              hipStream_t stream) {
    const float* x      = (const float*)d_in[0];
    const float* tables = (const float*)d_in[1];
    float2* out         = (float2*)d_out;

    int N = in_sizes[0] / 3;

    // Replicate Python's level-constant computation bit-exactly with libm doubles:
    //   b = exp((log(512) - log(16)) / 15); res_l = floor(16 * b**l)
    //   size_l = next_pow2(min(res_l^3, 2^19))
    Params p;
    double b = exp((log(512.0) - log(16.0)) / 15.0);
    for (int l = 0; l < N_LEVELS; ++l) {
        double r = floor(16.0 * pow(b, (double)l));
        long long res = (long long)r;
        long long cube = res * res * res;
        long long sz = cube < (long long)(1u << 19) ? cube : (long long)(1u << 19);
        unsigned int pw = 1;
        while ((long long)pw < sz) pw <<= 1;
        p.res[l]  = (float)r;
        p.mask[l] = pw - 1u;
    }

    size_t ws_needed = (size_t)N * N_LEVELS * sizeof(float2);  // 256 MB at N=2M
    int bpl = (N + 255) / 256;

    if (ws_size >= ws_needed) {
        // Level-phase-locked gather into workspace, then LDS transpose to out.
        dim3 grid1(bpl, N_LEVELS, 1);
        hashgrid_level_kernel<<<grid1, 256, 0, stream>>>(
            x, tables, (float2*)d_ws, p, N);
        transpose_kernel<<<bpl, 256, 0, stream>>>(
            (const float2*)d_ws, out, N);
    } else {
        // Workspace too small: original fused kernel (known-good, 1789 us).
        int total = N * N_LEVELS;
        int blocks = (total + 255) / 256;
        hashgrid_kernel<<<blocks, 256, 0, stream>>>(x, tables, out, p, total);
    }
}

// Round 4
// 984.273 us; speedup vs baseline: 1.8185x; 1.0263x over previous
//
#include <hip/hip_runtime.h>
#include <math.h>

#define N_LEVELS 16
#define MAX_SIZE (1u << 19)   // 2^19 entries per level slab in `tables`

typedef float f2v __attribute__((ext_vector_type(2)));  // native 8B vector for nt builtins

struct Params {
    float res[N_LEVELS];
    unsigned int mask[N_LEVELS];
    int lstart[N_LEVELS + 1];   // phase p covers levels [lstart[p], lstart[p+1])
};

// ---------------------------------------------------------------------------
// Phase 1: phase-major gather. Grid = (blocks_per_point_range, n_phases).
// Blocks are dispatched x-fastest, so the resident window at any instant
// covers ONE phase; each phase's tables fit within a single XCD's 4 MB L2
// (grouped under a 3.5 MB budget) -> gathers are L2 hits.
// Streams (x in, ws out) use nontemporal hints so they don't evict table
// lines or waste L2 residency. Output ws[l][n] (float2), coalesced.
// ---------------------------------------------------------------------------
__global__ __launch_bounds__(256) void hashgrid_phase_kernel(
    const float* __restrict__ x,
    const float* __restrict__ tables,
    float2* __restrict__ ws,          // [16][N] float2
    Params p, int N)
{
    int ph = blockIdx.y;
    int n = blockIdx.x * 256 + threadIdx.x;
    if (n >= N) return;

    float px = __builtin_nontemporal_load(x + (size_t)n * 3 + 0);
    float py = __builtin_nontemporal_load(x + (size_t)n * 3 + 1);
    float pz = __builtin_nontemporal_load(x + (size_t)n * 3 + 2);

    const unsigned int P2 = 2654435761u, P3 = 805459861u;

    int l0 = p.lstart[ph], l1 = p.lstart[ph + 1];
    for (int l = l0; l < l1; ++l) {
        float res = p.res[l];
        unsigned int mask = p.mask[l];
        const float2* __restrict__ tab =
            reinterpret_cast<const float2*>(tables) + (size_t)l * MAX_SIZE;

        // f32 semantics identical to reference: xs=x*res, xi=floor, xf=xs-xi
        float xs = px * res, ys = py * res, zs = pz * res;
        float fxi = floorf(xs), fyi = floorf(ys), fzi = floorf(zs);
        float wx1 = xs - fxi, wy1 = ys - fyi, wz1 = zs - fzi;
        float wx0 = 1.0f - wx1, wy0 = 1.0f - wy1, wz0 = 1.0f - wz1;

        unsigned int ix = (unsigned int)fxi;
        unsigned int iy = (unsigned int)fyi;
        unsigned int iz = (unsigned int)fzi;

        unsigned int hx0 = ix;       unsigned int hx1 = ix + 1u;
        unsigned int hy0 = iy * P2;  unsigned int hy1 = hy0 + P2;  // (iy+1)*P2 mod 2^32
        unsigned int hz0 = iz * P3;  unsigned int hz1 = hz0 + P3;

        unsigned int hidx[8];
        float w[8];
#pragma unroll
        for (int c = 0; c < 8; ++c) {
            unsigned int hh = ((c & 1) ? hx1 : hx0)
                            ^ ((c & 2) ? hy1 : hy0)
                            ^ ((c & 4) ? hz1 : hz0);
            hidx[c] = hh & mask;
            w[c] = (((c & 1) ? wx1 : wx0) * ((c & 2) ? wy1 : wy0)) * ((c & 4) ? wz1 : wz0);
        }

        // Issue all 8 gathers before use -> 8 outstanding loads per thread.
        float2 v[8];
#pragma unroll
        for (int c = 0; c < 8; ++c) v[c] = tab[hidx[c]];

        float accx = 0.0f, accy = 0.0f;
#pragma unroll
        for (int c = 0; c < 8; ++c) {   // sequential sum matches reference
            accx += v[c].x * w[c];
            accy += v[c].y * w[c];
        }

        f2v r; r.x = accx; r.y = accy;
        __builtin_nontemporal_store(
            r, reinterpret_cast<f2v*>(&ws[(size_t)l * N + n]));
    }
}

// ---------------------------------------------------------------------------
// Phase 2: transpose ws[l][n] -> out[n][l] via LDS tiles. Pure streaming,
// nontemporal both sides (no reuse).
// ---------------------------------------------------------------------------
__global__ __launch_bounds__(256) void transpose_kernel(
    const float2* __restrict__ ws,
    float2* __restrict__ out,
    int N)
{
    __shared__ float2 lds[N_LEVELS][257];   // +1 pad
    int tid = threadIdx.x;
    int n0 = blockIdx.x * 256;
    int n = n0 + tid;

#pragma unroll
    for (int l = 0; l < N_LEVELS; ++l) {
        if (n < N) {
            f2v v = __builtin_nontemporal_load(
                reinterpret_cast<const f2v*>(&ws[(size_t)l * N + n]));
            lds[l][tid] = make_float2(v.x, v.y);
        }
    }
    __syncthreads();

#pragma unroll
    for (int i = 0; i < 16; ++i) {
        int pn = i * 16 + (tid >> 4);   // point within tile
        int j  = tid & 15;              // level
        int np = n0 + pn;
        if (np < N) {
            float2 s = lds[j][pn];
            f2v v; v.x = s.x; v.y = s.y;
            __builtin_nontemporal_store(
                v, reinterpret_cast<f2v*>(&out[(size_t)np * 16 + j]));
        }
    }
}

// ---------------------------------------------------------------------------
// Fallback (original proven kernel): one thread per (point, level).
// ---------------------------------------------------------------------------
__global__ __launch_bounds__(256) void hashgrid_kernel(
    const float* __restrict__ x,
    const float* __restrict__ tables,
    float2* __restrict__ out,
    Params p, int total)
{
    int t = blockIdx.x * 256 + threadIdx.x;
    if (t >= total) return;
    int l = t & 15;
    int n = t >> 4;

    float res = p.res[l];
    unsigned int mask = p.mask[l];
    const float2* __restrict__ tab =
        reinterpret_cast<const float2*>(tables) + (size_t)l * MAX_SIZE;

    float px = x[n * 3 + 0];
    float py = x[n * 3 + 1];
    float pz = x[n * 3 + 2];

    float xs = px * res, ys = py * res, zs = pz * res;
    float fxi = floorf(xs), fyi = floorf(ys), fzi = floorf(zs);
    float wx1 = xs - fxi, wy1 = ys - fyi, wz1 = zs - fzi;
    float wx0 = 1.0f - wx1, wy0 = 1.0f - wy1, wz0 = 1.0f - wz1;

    unsigned int ix = (unsigned int)fxi;
    unsigned int iy = (unsigned int)fyi;
    unsigned int iz = (unsigned int)fzi;

    const unsigned int P2 = 2654435761u, P3 = 805459861u;
    unsigned int hx0 = ix;       unsigned int hx1 = ix + 1u;
    unsigned int hy0 = iy * P2;  unsigned int hy1 = hy0 + P2;
    unsigned int hz0 = iz * P3;  unsigned int hz1 = hz0 + P3;

    unsigned int hidx[8];
    float w[8];
#pragma unroll
    for (int c = 0; c < 8; ++c) {
        unsigned int hh = ((c & 1) ? hx1 : hx0)
                        ^ ((c & 2) ? hy1 : hy0)
                        ^ ((c & 4) ? hz1 : hz0);
        hidx[c] = hh & mask;
        w[c] = (((c & 1) ? wx1 : wx0) * ((c & 2) ? wy1 : wy0)) * ((c & 4) ? wz1 : wz0);
    }

    float2 v[8];
#pragma unroll
    for (int c = 0; c < 8; ++c) v[c] = tab[hidx[c]];

    float accx = 0.0f, accy = 0.0f;
#pragma unroll
    for (int c = 0; c < 8; ++c) {
        accx += v[c].x * w[c];
        accy += v[c].y * w[c];
    }

    out[t] = make_float2(accx, accy);
}

extern "C" void kernel_launch(void* const* d_in, const int* in_sizes, int n_in,
                              void* d_out, int out_size, void* d_ws, size_t ws_size,
                              hipStream_t stream) {
    const float* x      = (const float*)d_in[0];
    const float* tables = (const float*)d_in[1];
    float2* out         = (float2*)d_out;

    int N = in_sizes[0] / 3;

    // Replicate Python's level-constant computation bit-exactly with libm doubles.
    Params p;
    double b = exp((log(512.0) - log(16.0)) / 15.0);
    for (int l = 0; l < N_LEVELS; ++l) {
        double r = floor(16.0 * pow(b, (double)l));
        long long res = (long long)r;
        long long cube = res * res * res;
        long long sz = cube < (long long)(1u << 19) ? cube : (long long)(1u << 19);
        unsigned int pw = 1;
        while ((long long)pw < sz) pw <<= 1;
        p.res[l]  = (float)r;
        p.mask[l] = pw - 1u;
    }

    // Group levels into phases whose combined table bytes fit an L2 budget.
    // Coarse levels merge (fewer phases -> fewer x re-reads, fewer tails);
    // fine 4 MB levels stay solo.
    const size_t BUDGET = (size_t)(7u << 19);   // 3.5 MB of 4 MB per-XCD L2
    int np = 0;
    size_t acc = 0;
    bool open = false;
    for (int l = 0; l < N_LEVELS; ++l) {
        size_t tb = ((size_t)p.mask[l] + 1) * sizeof(float2);
        if (open && acc + tb <= BUDGET) {
            acc += tb;
        } else {
            p.lstart[np++] = l;
            acc = tb;
            open = true;
        }
    }
    p.lstart[np] = N_LEVELS;

    size_t ws_needed = (size_t)N * N_LEVELS * sizeof(float2);  // 256 MB at N=2M
    int bpl = (N + 255) / 256;

    if (ws_size >= ws_needed) {
        dim3 grid1(bpl, np, 1);
        hashgrid_phase_kernel<<<grid1, 256, 0, stream>>>(
            x, tables, (float2*)d_ws, p, N);
        transpose_kernel<<<bpl, 256, 0, stream>>>(
            (const float2*)d_ws, out, N);
    } else {
        // Workspace too small: original fused kernel (known-good, 1789 us).
        int total = N * N_LEVELS;
        int blocks = (total + 255) / 256;
        hashgrid_kernel<<<blocks, 256, 0, stream>>>(x, tables, out, p, total);
    }
}